// Round 4
// baseline (381.886 us; speedup 1.0000x reference)
//
#include <hip/hip_runtime.h>

#define M_DIM 16384
#define N_DIM 4096
#define K_DIM 4096
#define NT 32            // K_DIM / BK, BK = 128 bytes (int8)

typedef __attribute__((ext_vector_type(4)))  float f32x4;
typedef __attribute__((ext_vector_type(8)))  short bf16x8;
typedef __attribute__((ext_vector_type(4)))  int   i32x4;
typedef __attribute__((ext_vector_type(16))) int   i32x16;

__device__ __forceinline__ short f2bf(float f) {
    unsigned int u = __builtin_bit_cast(unsigned int, f);
    u += 0x7FFFu + ((u >> 16) & 1u);
    return (short)(u >> 16);
}

// ---- merged preprocessing: blocks [0,16384) quantize x rows; rest pack w ----
__global__ __launch_bounds__(256)
void quant_kernel(const float* __restrict__ x, const int* __restrict__ q,
                  char* __restrict__ x8, char* __restrict__ w8,
                  float* __restrict__ rs) {
    const int tid = threadIdx.x;
    if (blockIdx.x < M_DIM) {
        const int row = blockIdx.x;
        const float* xr = x + (size_t)row * K_DIM;
        f32x4 v[4];
        float am = 0.f;
#pragma unroll
        for (int p = 0; p < 4; ++p) {
            v[p] = *(const f32x4*)(xr + p * 1024 + tid * 4);
#pragma unroll
            for (int e = 0; e < 4; ++e) am = fmaxf(am, fabsf(v[p][e]));
        }
#pragma unroll
        for (int off = 32; off >= 1; off >>= 1)
            am = fmaxf(am, __shfl_xor(am, off, 64));
        __shared__ float smax[4];
        if ((tid & 63) == 0) smax[tid >> 6] = am;
        __syncthreads();
        am = fmaxf(fmaxf(smax[0], smax[1]), fmaxf(smax[2], smax[3]));
        const float inv = am > 0.f ? 127.f / am : 0.f;
        if (tid == 0) rs[row] = am / 127.f;
        int* o32 = (int*)(x8 + (size_t)row * K_DIM);
#pragma unroll
        for (int p = 0; p < 4; ++p) {
            const int b0 = (int)rintf(v[p][0] * inv);
            const int b1 = (int)rintf(v[p][1] * inv);
            const int b2 = (int)rintf(v[p][2] * inv);
            const int b3 = (int)rintf(v[p][3] * inv);
            o32[p * 256 + tid] = (b0 & 255) | ((b1 & 255) << 8) | ((b2 & 255) << 16) | ((b3 & 255) << 24);
        }
    } else {
        const long n = (long)N_DIM * K_DIM;
        long i = ((long)(blockIdx.x - M_DIM) * 256 + tid) * 16;
        const long stride = 2048L * 256 * 16;
        for (; i < n; i += stride) {
            i32x4 o;
#pragma unroll
            for (int j = 0; j < 4; ++j) {
                i32x4 a = *(const i32x4*)(q + i + j * 4);
                o[j] = (a[0] & 255) | ((a[1] & 255) << 8) | ((a[2] & 255) << 16) | ((a[3] & 255) << 24);
            }
            *(i32x4*)(w8 + i) = o;
        }
    }
}

__device__ __forceinline__ void load_lds16(const void* g, void* l) {
    __builtin_amdgcn_global_load_lds((const __attribute__((address_space(1))) void*)g,
                                     (__attribute__((address_space(3))) void*)l, 16, 0, 0);
}

#define BAR() __builtin_amdgcn_s_barrier()
#define VM(n) asm volatile("s_waitcnt vmcnt(" #n ")" ::: "memory")

// ============ 256x256 8-phase int8 GEMM, 32x32x32 MFMA ============
// C[m][n] = sum_k x8[m][k]*w8[n][k] (exact i32); y = C * rs[m]*scales[n] + bias[n].
// LDS regions (128B rows, 8x16B slots, slot ^= row&7 via pre-swizzled source):
//   0=A q0, 1=A q1 (region q: ht-row = wm*64 + mf*32 + (lane&31))
//   2=B nh0, 3=B nh1 (ht-row = wn*32 + (lane&31))
// Fragments (32x32x32 i8): A row=lane&31, k=(lane>>5)*16+e; B col=lane&31 same k.
// C/D: col=lane&31, row=(reg&3)+8*(reg>>2)+4*(lane>>5)  [m74/m101 verified].
__global__ __launch_bounds__(512, 2)
void gemm8p_i8(const char* __restrict__ A, const char* __restrict__ Bw,
               const float* __restrict__ rs, const float* __restrict__ scales,
               const float* __restrict__ bias, float* __restrict__ out) {
    __shared__ char lds[2][4][128 * 128];   // 128 KiB

    const int tid  = threadIdx.x;
    const int lane = tid & 63;
    const int w    = tid >> 6;
    const int wm   = w >> 2;
    const int wn   = w & 3;
    const int l31  = lane & 31;
    const int kg   = lane >> 5;
    const int sx   = lane & 7;

    const int nwg = gridDim.x;
    const int swz = (blockIdx.x & 7) * (nwg >> 3) + (blockIdx.x >> 3);
    const int bn  = (swz & 15) * 256;
    const int bm  = (swz >> 4) * 256;

    const char* aS[2];
    const char* bS[2];
#pragma unroll
    for (int L = 0; L < 2; ++L) {
        const int c   = L * 512 + tid;
        const int row = c >> 3;
        const int kc  = (c & 7) ^ (row & 7);
        const int mA  = bm + ((row >> 6) << 7) + (row & 63);
        const int nB  = bn + ((row >> 5) << 6) + (row & 31);
        aS[L] = A  + (size_t)mA * K_DIM + kc * 16;
        bS[L] = Bw + (size_t)nB * K_DIM + kc * 16;
    }
    const int wofs = w << 10;

#define STAGE_A(buf, q, kt) do { \
    char* d = &lds[buf][q][wofs]; \
    const long ko = (long)(kt) * 128 + (long)(q) * (64 * (long)K_DIM); \
    load_lds16(aS[0] + ko, d); \
    load_lds16(aS[1] + ko, d + 8192); \
} while (0)

#define STAGE_B(buf, nh, kt) do { \
    char* d = &lds[buf][2 + (nh)][wofs]; \
    const long ko = (long)(kt) * 128 + (long)(nh) * (32 * (long)K_DIM); \
    load_lds16(bS[0] + ko, d); \
    load_lds16(bS[1] + ko, d + 8192); \
} while (0)

    // 32x32 fragment reads: region row*128 + swizzled 16B slot
#define RD_A(buf, q, mf, ks) \
    (*(const i32x4*)&lds[buf][q][(((wm << 6) + (mf) * 32 + l31) << 7) + (((((ks) << 1) + kg) ^ sx) << 4)])
#define RD_B(buf, nh, ks) \
    (*(const i32x4*)&lds[buf][2 + (nh)][(((wn << 5) + l31) << 7) + (((((ks) << 1) + kg) ^ sx) << 4)])

    i32x16 acc[4][2];
#pragma unroll
    for (int i = 0; i < 4; ++i)
#pragma unroll
        for (int j = 0; j < 2; ++j)
#pragma unroll
            for (int r = 0; r < 16; ++r) acc[i][j][r] = 0;

    i32x4 aF[2][4], bF0[4], bF1[4];

#define LOAD_AF(buf, q) do { \
    _Pragma("unroll") for (int mf = 0; mf < 2; ++mf) \
    _Pragma("unroll") for (int ks = 0; ks < 4; ++ks) aF[mf][ks] = RD_A(buf, q, mf, ks); \
} while (0)
#define LOAD_BF(dst, buf, nh) do { \
    _Pragma("unroll") for (int ks = 0; ks < 4; ++ks) dst[ks] = RD_B(buf, nh, ks); \
} while (0)
#define MMA_Q(q, nh, BREG) do { \
    __builtin_amdgcn_s_setprio(1); \
    _Pragma("unroll") for (int ks = 0; ks < 4; ++ks) \
    _Pragma("unroll") for (int mf = 0; mf < 2; ++mf) \
        acc[(q) * 2 + mf][nh] = __builtin_amdgcn_mfma_i32_32x32x32_i8( \
            aF[mf][ks], BREG[ks], acc[(q) * 2 + mf][nh], 0, 0, 0); \
    __builtin_amdgcn_s_setprio(0); \
} while (0)

#define PHASES(kt, S1, S2, S3, S4, S5, S6, S7, S8, VMA, VMB) do { \
    LOAD_AF(0, 0); LOAD_BF(bF0, 0, 0); \
    S1; BAR(); MMA_Q(0, 0, bF0); BAR(); \
    LOAD_BF(bF1, 0, 1); \
    S2; BAR(); MMA_Q(0, 1, bF1); BAR(); \
    LOAD_AF(0, 1); \
    S3; BAR(); MMA_Q(1, 0, bF0); BAR(); \
    S4; VMA; BAR(); MMA_Q(1, 1, bF1); BAR(); \
    LOAD_AF(1, 0); LOAD_BF(bF0, 1, 0); \
    S5; BAR(); MMA_Q(0, 0, bF0); BAR(); \
    LOAD_BF(bF1, 1, 1); \
    S6; BAR(); MMA_Q(0, 1, bF1); BAR(); \
    LOAD_AF(1, 1); \
    S7; BAR(); MMA_Q(1, 0, bF0); BAR(); \
    S8; VMB; BAR(); MMA_Q(1, 1, bF1); BAR(); \
} while (0)

    // prologue: tile0 -> buf0 (4 ht), tile1 -> buf1 (first 3 ht)
    STAGE_A(0, 0, 0); STAGE_A(0, 1, 0); STAGE_B(0, 0, 0); STAGE_B(0, 1, 0);
    STAGE_A(1, 0, 1); STAGE_B(1, 0, 1); STAGE_B(1, 1, 1);
    VM(6);
    BAR();

    for (int it = 0; it < 15; ++it) {
        const int kt = it * 2;
        PHASES(kt,
               STAGE_A(1, 1, kt + 1),
               STAGE_A(0, 0, kt + 2),
               STAGE_B(0, 0, kt + 2),
               STAGE_B(0, 1, kt + 2),
               STAGE_A(0, 1, kt + 2),
               STAGE_A(1, 0, kt + 3),
               STAGE_B(1, 0, kt + 3),
               STAGE_B(1, 1, kt + 3),
               VM(6), VM(6));
    }
    // tail: kt = 30 — only A1(31) staged; drain at P4
    PHASES(30, STAGE_A(1, 1, 31), , , , , , , , VM(0), );

    // ---- transposed epilogue: per-wave 4KB LDS scratch, dwordx4 stores ----
    float* scratch = (float*)(&lds[0][0][0]) + w * 1024;
#pragma unroll
    for (int mfg = 0; mfg < 4; ++mfg) {
        const int gr0 = bm + (wm << 7) + mfg * 32;
#pragma unroll
        for (int nf = 0; nf < 2; ++nf) {
            const int gc0 = bn + (wn << 6) + nf * 32;
#pragma unroll
            for (int r = 0; r < 16; ++r) {
                const int row = (r & 3) + ((r >> 2) << 3) + (kg << 2);
                scratch[row * 32 + l31] = (float)acc[mfg][nf][r];
            }
            const int colq = (lane & 7) * 4;
            const f32x4 sc = *(const f32x4*)&scales[gc0 + colq];
            const f32x4 bb = *(const f32x4*)&bias[gc0 + colq];
#pragma unroll
            for (int s = 0; s < 4; ++s) {
                const int row_l = s * 8 + (lane >> 3);
                f32x4 v = *(const f32x4*)&scratch[row_l * 32 + colq];
                const float rsv = rs[gr0 + row_l];
                f32x4 o;
#pragma unroll
                for (int e = 0; e < 4; ++e) o[e] = v[e] * (rsv * sc[e]) + bb[e];
                *(f32x4*)&out[(size_t)(gr0 + row_l) * N_DIM + gc0 + colq] = o;
            }
        }
    }
#undef STAGE_A
#undef STAGE_B
#undef RD_A
#undef RD_B
#undef LOAD_AF
#undef LOAD_BF
#undef MMA_Q
#undef PHASES
}

// ============ fallback (ws too small): reg-staged bf16, known-correct ============
__global__ __launch_bounds__(256)
void gemm_fallback(const float* __restrict__ Xf, const int* __restrict__ Qw,
                   const float* __restrict__ scales, const float* __restrict__ bias,
                   float* __restrict__ out) {
    __shared__ short a_lds[128 * 64];
    __shared__ short b_lds[128 * 64];
    const int tid  = threadIdx.x;
    const int lane = tid & 63;
    const int wid  = tid >> 6;
    const int wm   = wid >> 1;
    const int wn   = wid & 1;
    const int bn = (blockIdx.x % (N_DIM / 128)) * 128;
    const int bm = (blockIdx.x / (N_DIM / 128)) * 128;
    const int lrow = lane & 15;
    const int lkg  = lane >> 4;

    f32x4 acc[4][4];
#pragma unroll
    for (int i = 0; i < 4; ++i)
#pragma unroll
        for (int j = 0; j < 4; ++j)
            acc[i][j] = (f32x4){0.f, 0.f, 0.f, 0.f};

    for (int k0 = 0; k0 < K_DIM; k0 += 64) {
#pragma unroll
        for (int t = 0; t < 4; ++t) {
            const int ch  = t * 256 + tid;
            const int row = ch >> 3;
            const int kc  = (ch & 7) ^ (row & 7);
            {
                const float* sa = Xf + (size_t)(bm + row) * K_DIM + k0 + kc * 8;
                f32x4 a0 = *(const f32x4*)sa;
                f32x4 a1 = *(const f32x4*)(sa + 4);
                bf16x8 r;
                r[0] = f2bf(a0[0]); r[1] = f2bf(a0[1]); r[2] = f2bf(a0[2]); r[3] = f2bf(a0[3]);
                r[4] = f2bf(a1[0]); r[5] = f2bf(a1[1]); r[6] = f2bf(a1[2]); r[7] = f2bf(a1[3]);
                *(bf16x8*)&a_lds[ch * 8] = r;
            }
            {
                const int* sb = Qw + (size_t)(bn + row) * K_DIM + k0 + kc * 8;
                i32x4 q0 = *(const i32x4*)sb;
                i32x4 q1 = *(const i32x4*)(sb + 4);
                bf16x8 r;
                r[0] = f2bf((float)q0[0]); r[1] = f2bf((float)q0[1]);
                r[2] = f2bf((float)q0[2]); r[3] = f2bf((float)q0[3]);
                r[4] = f2bf((float)q1[0]); r[5] = f2bf((float)q1[1]);
                r[6] = f2bf((float)q1[2]); r[7] = f2bf((float)q1[3]);
                *(bf16x8*)&b_lds[ch * 8] = r;
            }
        }
        __syncthreads();
#pragma unroll
        for (int ks = 0; ks < 2; ++ks) {
            const int kgl = ks * 4 + lkg;
            bf16x8 af[4], bfr[4];
#pragma unroll
            for (int i = 0; i < 4; ++i) {
                const int am = wm * 64 + i * 16 + lrow;
                af[i]  = *(const bf16x8*)&a_lds[am * 64 + ((kgl ^ (am & 7)) << 3)];
                const int bnn = wn * 64 + i * 16 + lrow;
                bfr[i] = *(const bf16x8*)&b_lds[bnn * 64 + ((kgl ^ (bnn & 7)) << 3)];
            }
#pragma unroll
            for (int i = 0; i < 4; ++i)
#pragma unroll
                for (int j = 0; j < 4; ++j)
                    acc[i][j] = __builtin_amdgcn_mfma_f32_16x16x32_bf16(af[i], bfr[j], acc[i][j], 0, 0, 0);
        }
        __syncthreads();
    }
#pragma unroll
    for (int j = 0; j < 4; ++j) {
        const int col = bn + wn * 64 + j * 16 + lrow;
        const float s  = scales[col];
        const float bb = bias[col];
#pragma unroll
        for (int i = 0; i < 4; ++i) {
            const int row0 = bm + wm * 64 + i * 16 + lkg * 4;
#pragma unroll
            for (int r = 0; r < 4; ++r)
                out[(size_t)(row0 + r) * N_DIM + col] = acc[i][j][r] * s + bb;
        }
    }
}

extern "C" void kernel_launch(void* const* d_in, const int* in_sizes, int n_in,
                              void* d_out, int out_size, void* d_ws, size_t ws_size,
                              hipStream_t stream) {
    const float* x      = (const float*)d_in[0];
    const int*   qw     = (const int*)d_in[1];
    const float* scales = (const float*)d_in[2];
    const float* bias   = (const float*)d_in[3];
    float* out = (float*)d_out;

    const size_t x_elems = (size_t)M_DIM * K_DIM;
    const size_t w_elems = (size_t)N_DIM * K_DIM;
    const size_t need    = x_elems + w_elems + M_DIM * sizeof(float);

    if (ws_size >= need) {
        char*  x8 = (char*)d_ws;
        char*  w8 = x8 + x_elems;
        float* rs = (float*)(w8 + w_elems);
        quant_kernel<<<M_DIM + 2048, 256, 0, stream>>>(x, qw, x8, w8, rs);
        const dim3 grid((M_DIM / 256) * (N_DIM / 256));   // 1024 blocks
        gemm8p_i8<<<grid, 512, 0, stream>>>(x8, w8, rs, scales, bias, out);
    } else {
        const dim3 grid((M_DIM / 128) * (N_DIM / 128));
        gemm_fallback<<<grid, 256, 0, stream>>>(x, qw, scales, bias, out);
    }
}

// Round 5
// 336.956 us; speedup vs baseline: 1.1333x; 1.1333x over previous
//
#include <hip/hip_runtime.h>

#define M_DIM 16384
#define N_DIM 4096
#define K_DIM 4096
#define NT 32            // K_DIM / BK, BK = 128 bytes (int8)

typedef __attribute__((ext_vector_type(4))) float f32x4;
typedef __attribute__((ext_vector_type(8))) short bf16x8;
typedef __attribute__((ext_vector_type(4))) int   i32x4;

__device__ __forceinline__ short f2bf(float f) {
    unsigned int u = __builtin_bit_cast(unsigned int, f);
    u += 0x7FFFu + ((u >> 16) & 1u);
    return (short)(u >> 16);
}

// ---- merged preprocessing: blocks [0,16384) quantize x rows; rest pack w ----
__global__ __launch_bounds__(256)
void quant_kernel(const float* __restrict__ x, const int* __restrict__ q,
                  char* __restrict__ x8, char* __restrict__ w8,
                  float* __restrict__ rs) {
    const int tid = threadIdx.x;
    if (blockIdx.x < M_DIM) {
        const int row = blockIdx.x;
        const float* xr = x + (size_t)row * K_DIM;
        f32x4 v[4];
        float am = 0.f;
#pragma unroll
        for (int p = 0; p < 4; ++p) {
            v[p] = *(const f32x4*)(xr + p * 1024 + tid * 4);
#pragma unroll
            for (int e = 0; e < 4; ++e) am = fmaxf(am, fabsf(v[p][e]));
        }
#pragma unroll
        for (int off = 32; off >= 1; off >>= 1)
            am = fmaxf(am, __shfl_xor(am, off, 64));
        __shared__ float smax[4];
        if ((tid & 63) == 0) smax[tid >> 6] = am;
        __syncthreads();
        am = fmaxf(fmaxf(smax[0], smax[1]), fmaxf(smax[2], smax[3]));
        const float inv = am > 0.f ? 127.f / am : 0.f;
        if (tid == 0) rs[row] = am / 127.f;
        int* o32 = (int*)(x8 + (size_t)row * K_DIM);
#pragma unroll
        for (int p = 0; p < 4; ++p) {
            const int b0 = (int)rintf(v[p][0] * inv);
            const int b1 = (int)rintf(v[p][1] * inv);
            const int b2 = (int)rintf(v[p][2] * inv);
            const int b3 = (int)rintf(v[p][3] * inv);
            o32[p * 256 + tid] = (b0 & 255) | ((b1 & 255) << 8) | ((b2 & 255) << 16) | ((b3 & 255) << 24);
        }
    } else {
        const long n = (long)N_DIM * K_DIM;
        long i = ((long)(blockIdx.x - M_DIM) * 256 + tid) * 16;
        const long stride = 2048L * 256 * 16;
        for (; i < n; i += stride) {
            i32x4 o;
#pragma unroll
            for (int j = 0; j < 4; ++j) {
                i32x4 a = *(const i32x4*)(q + i + j * 4);
                o[j] = (a[0] & 255) | ((a[1] & 255) << 8) | ((a[2] & 255) << 16) | ((a[3] & 255) << 24);
            }
            *(i32x4*)(w8 + i) = o;
        }
    }
}

__device__ __forceinline__ void load_lds16(const void* g, void* l) {
    __builtin_amdgcn_global_load_lds((const __attribute__((address_space(1))) void*)g,
                                     (__attribute__((address_space(3))) void*)l, 16, 0, 0);
}

#define BAR() __builtin_amdgcn_s_barrier()
#define VM(n) asm volatile("s_waitcnt vmcnt(" #n ")" ::: "memory")

// ============ 256x256 8-phase int8 GEMM, 16x16x64 MFMA (R3 geometry) ============
// C[m][n] = sum_k x8[m][k]*w8[n][k] (exact i32); y = C * rs[m]*scales[n] + bias[n].
// LDS regions (128B rows, 8x16B slots, slot ^= row&7 via pre-swizzled source).
// Fragment reads use the R3 16-row / 4-slot-group pattern (measured 0 conflicts);
// the 32-row / 2-slot-group 32x32 pattern measured ~4-way conflicts (R4) — avoid.
__global__ __launch_bounds__(512, 2)
void gemm8p_i8(const char* __restrict__ A, const char* __restrict__ Bw,
               const float* __restrict__ rs, const float* __restrict__ scales,
               const float* __restrict__ bias, float* __restrict__ out) {
    __shared__ char lds[2][4][128 * 128];   // 128 KiB

    const int tid  = threadIdx.x;
    const int lane = tid & 63;
    const int w    = tid >> 6;
    const int wm   = w >> 2;
    const int wn   = w & 3;
    const int lrow = lane & 15;
    const int lkg  = lane >> 4;
    const int sx   = lane & 7;

    const int nwg = gridDim.x;
    const int swz = (blockIdx.x & 7) * (nwg >> 3) + (blockIdx.x >> 3);
    const int bn  = (swz & 15) * 256;
    const int bm  = (swz >> 4) * 256;

    const char* aS[2];
    const char* bS[2];
#pragma unroll
    for (int L = 0; L < 2; ++L) {
        const int c   = L * 512 + tid;
        const int row = c >> 3;
        const int kc  = (c & 7) ^ (row & 7);
        const int mA  = bm + ((row >> 6) << 7) + (row & 63);
        const int nB  = bn + ((row >> 5) << 6) + (row & 31);
        aS[L] = A  + (size_t)mA * K_DIM + kc * 16;
        bS[L] = Bw + (size_t)nB * K_DIM + kc * 16;
    }
    const int wofs = w << 10;   // wave byte base, L=0

#define STAGE_A(buf, q, kt) do { \
    char* d = &lds[buf][q][wofs]; \
    const long ko = (long)(kt) * 128 + (long)(q) * (64 * (long)K_DIM); \
    load_lds16(aS[0] + ko, d); \
    load_lds16(aS[1] + ko, d + 8192); \
} while (0)

#define STAGE_B(buf, nh, kt) do { \
    char* d = &lds[buf][2 + (nh)][wofs]; \
    const long ko = (long)(kt) * 128 + (long)(nh) * (32 * (long)K_DIM); \
    load_lds16(bS[0] + ko, d); \
    load_lds16(bS[1] + ko, d + 8192); \
} while (0)

    const int aoff = (wm << 6) + lrow;
    const int boff = (wn << 5) + lrow;

#define RD_A(buf, q, sub, ks) \
    (*(const i32x4*)&lds[buf][q][((aoff + (sub) * 16) << 7) + (((((ks) << 2) + lkg) ^ sx) << 4)])
#define RD_B(buf, nh, sub, ks) \
    (*(const i32x4*)&lds[buf][2 + (nh)][((boff + (sub) * 16) << 7) + (((((ks) << 2) + lkg) ^ sx) << 4)])

    i32x4 acc[8][4];
#pragma unroll
    for (int i = 0; i < 8; ++i)
#pragma unroll
        for (int j = 0; j < 4; ++j)
            acc[i][j] = (i32x4){0, 0, 0, 0};

    i32x4 aF[4][2], bF0[2][2], bF1[2][2];

#define LOAD_AF(buf, q) do { \
    _Pragma("unroll") for (int ii = 0; ii < 4; ++ii) { \
        aF[ii][0] = RD_A(buf, q, ii, 0); aF[ii][1] = RD_A(buf, q, ii, 1); } \
} while (0)
#define LOAD_BF(dst, buf, nh) do { \
    _Pragma("unroll") for (int jj = 0; jj < 2; ++jj) { \
        dst[jj][0] = RD_B(buf, nh, jj, 0); dst[jj][1] = RD_B(buf, nh, jj, 1); } \
} while (0)
#define MMA_Q(mh, nh, BREG) do { \
    __builtin_amdgcn_s_setprio(1); \
    _Pragma("unroll") for (int ii = 0; ii < 4; ++ii) \
    _Pragma("unroll") for (int jj = 0; jj < 2; ++jj) \
    _Pragma("unroll") for (int ks = 0; ks < 2; ++ks) \
        acc[(mh) * 4 + ii][(nh) * 2 + jj] = __builtin_amdgcn_mfma_i32_16x16x64_i8( \
            aF[ii][ks], BREG[jj][ks], acc[(mh) * 4 + ii][(nh) * 2 + jj], 0, 0, 0); \
    __builtin_amdgcn_s_setprio(0); \
} while (0)

#define PHASES(kt, S1, S2, S3, S4, S5, S6, S7, S8, VMA, VMB) do { \
    LOAD_AF(0, 0); LOAD_BF(bF0, 0, 0); \
    S1; BAR(); MMA_Q(0, 0, bF0); BAR(); \
    LOAD_BF(bF1, 0, 1); \
    S2; BAR(); MMA_Q(0, 1, bF1); BAR(); \
    LOAD_AF(0, 1); \
    S3; BAR(); MMA_Q(1, 0, bF0); BAR(); \
    S4; VMA; BAR(); MMA_Q(1, 1, bF1); BAR(); \
    LOAD_AF(1, 0); LOAD_BF(bF0, 1, 0); \
    S5; BAR(); MMA_Q(0, 0, bF0); BAR(); \
    LOAD_BF(bF1, 1, 1); \
    S6; BAR(); MMA_Q(0, 1, bF1); BAR(); \
    LOAD_AF(1, 1); \
    S7; BAR(); MMA_Q(1, 0, bF0); BAR(); \
    S8; VMB; BAR(); MMA_Q(1, 1, bF1); BAR(); \
} while (0)

    // prologue: tile0 -> buf0 (4 ht), tile1 -> buf1 (first 3 ht)
    STAGE_A(0, 0, 0); STAGE_A(0, 1, 0); STAGE_B(0, 0, 0); STAGE_B(0, 1, 0);
    STAGE_A(1, 0, 1); STAGE_B(1, 0, 1); STAGE_B(1, 1, 1);
    VM(6);
    BAR();

    for (int it = 0; it < 15; ++it) {
        const int kt = it * 2;
        PHASES(kt,
               STAGE_A(1, 1, kt + 1),
               STAGE_A(0, 0, kt + 2),
               STAGE_B(0, 0, kt + 2),
               STAGE_B(0, 1, kt + 2),
               STAGE_A(0, 1, kt + 2),
               STAGE_A(1, 0, kt + 3),
               STAGE_B(1, 0, kt + 3),
               STAGE_B(1, 1, kt + 3),
               VM(6), VM(6));
    }
    // tail: kt = 30 — only A1(31) staged; drain at P4
    PHASES(30, STAGE_A(1, 1, 31), , , , , , , , VM(0), );

    // epilogue: y = idot * (rs[row]*scales[col]) + bias[col]; nt stores keep
    // the 256MB output stream from evicting x8/w8 out of L3.
#pragma unroll
    for (int i = 0; i < 8; ++i) {
        const int r0 = bm + (wm << 7) + i * 16 + (lkg << 2);
        const f32x4 rsv = *(const f32x4*)&rs[r0];
#pragma unroll
        for (int j = 0; j < 4; ++j) {
            const int col = bn + (wn << 6) + j * 16 + lrow;
            const float sc = scales[col];
            const float bb = bias[col];
#pragma unroll
            for (int r = 0; r < 4; ++r)
                __builtin_nontemporal_store((float)acc[i][j][r] * (rsv[r] * sc) + bb,
                                            &out[(size_t)(r0 + r) * N_DIM + col]);
        }
    }
#undef STAGE_A
#undef STAGE_B
#undef RD_A
#undef RD_B
#undef LOAD_AF
#undef LOAD_BF
#undef MMA_Q
#undef PHASES
}

// ============ fallback (ws too small): reg-staged bf16, known-correct ============
__global__ __launch_bounds__(256)
void gemm_fallback(const float* __restrict__ Xf, const int* __restrict__ Qw,
                   const float* __restrict__ scales, const float* __restrict__ bias,
                   float* __restrict__ out) {
    __shared__ short a_lds[128 * 64];
    __shared__ short b_lds[128 * 64];
    const int tid  = threadIdx.x;
    const int lane = tid & 63;
    const int wid  = tid >> 6;
    const int wm   = wid >> 1;
    const int wn   = wid & 1;
    const int bn = (blockIdx.x % (N_DIM / 128)) * 128;
    const int bm = (blockIdx.x / (N_DIM / 128)) * 128;
    const int lrow = lane & 15;
    const int lkg  = lane >> 4;

    f32x4 acc[4][4];
#pragma unroll
    for (int i = 0; i < 4; ++i)
#pragma unroll
        for (int j = 0; j < 4; ++j)
            acc[i][j] = (f32x4){0.f, 0.f, 0.f, 0.f};

    for (int k0 = 0; k0 < K_DIM; k0 += 64) {
#pragma unroll
        for (int t = 0; t < 4; ++t) {
            const int ch  = t * 256 + tid;
            const int row = ch >> 3;
            const int kc  = (ch & 7) ^ (row & 7);
            {
                const float* sa = Xf + (size_t)(bm + row) * K_DIM + k0 + kc * 8;
                f32x4 a0 = *(const f32x4*)sa;
                f32x4 a1 = *(const f32x4*)(sa + 4);
                bf16x8 r;
                r[0] = f2bf(a0[0]); r[1] = f2bf(a0[1]); r[2] = f2bf(a0[2]); r[3] = f2bf(a0[3]);
                r[4] = f2bf(a1[0]); r[5] = f2bf(a1[1]); r[6] = f2bf(a1[2]); r[7] = f2bf(a1[3]);
                *(bf16x8*)&a_lds[ch * 8] = r;
            }
            {
                const int* sb = Qw + (size_t)(bn + row) * K_DIM + k0 + kc * 8;
                i32x4 q0 = *(const i32x4*)sb;
                i32x4 q1 = *(const i32x4*)(sb + 4);
                bf16x8 r;
                r[0] = f2bf((float)q0[0]); r[1] = f2bf((float)q0[1]);
                r[2] = f2bf((float)q0[2]); r[3] = f2bf((float)q0[3]);
                r[4] = f2bf((float)q1[0]); r[5] = f2bf((float)q1[1]);
                r[6] = f2bf((float)q1[2]); r[7] = f2bf((float)q1[3]);
                *(bf16x8*)&b_lds[ch * 8] = r;
            }
        }
        __syncthreads();
#pragma unroll
        for (int ks = 0; ks < 2; ++ks) {
            const int kgl = ks * 4 + lkg;
            bf16x8 af[4], bfr[4];
#pragma unroll
            for (int i = 0; i < 4; ++i) {
                const int am = wm * 64 + i * 16 + lrow;
                af[i]  = *(const bf16x8*)&a_lds[am * 64 + ((kgl ^ (am & 7)) << 3)];
                const int bnn = wn * 64 + i * 16 + lrow;
                bfr[i] = *(const bf16x8*)&b_lds[bnn * 64 + ((kgl ^ (bnn & 7)) << 3)];
            }
#pragma unroll
            for (int i = 0; i < 4; ++i)
#pragma unroll
                for (int j = 0; j < 4; ++j)
                    acc[i][j] = __builtin_amdgcn_mfma_f32_16x16x32_bf16(af[i], bfr[j], acc[i][j], 0, 0, 0);
        }
        __syncthreads();
    }
#pragma unroll
    for (int j = 0; j < 4; ++j) {
        const int col = bn + wn * 64 + j * 16 + lrow;
        const float s  = scales[col];
        const float bb = bias[col];
#pragma unroll
        for (int i = 0; i < 4; ++i) {
            const int row0 = bm + wm * 64 + i * 16 + lkg * 4;
#pragma unroll
            for (int r = 0; r < 4; ++r)
                out[(size_t)(row0 + r) * N_DIM + col] = acc[i][j][r] * s + bb;
        }
    }
}

extern "C" void kernel_launch(void* const* d_in, const int* in_sizes, int n_in,
                              void* d_out, int out_size, void* d_ws, size_t ws_size,
                              hipStream_t stream) {
    const float* x      = (const float*)d_in[0];
    const int*   qw     = (const int*)d_in[1];
    const float* scales = (const float*)d_in[2];
    const float* bias   = (const float*)d_in[3];
    float* out = (float*)d_out;

    const size_t x_elems = (size_t)M_DIM * K_DIM;
    const size_t w_elems = (size_t)N_DIM * K_DIM;
    const size_t need    = x_elems + w_elems + M_DIM * sizeof(float);

    if (ws_size >= need) {
        char*  x8 = (char*)d_ws;
        char*  w8 = x8 + x_elems;
        float* rs = (float*)(w8 + w_elems);
        quant_kernel<<<M_DIM + 2048, 256, 0, stream>>>(x, qw, x8, w8, rs);
        const dim3 grid((M_DIM / 256) * (N_DIM / 256));   // 1024 blocks
        gemm8p_i8<<<grid, 512, 0, stream>>>(x8, w8, rs, scales, bias, out);
    } else {
        const dim3 grid((M_DIM / 128) * (N_DIM / 128));
        gemm_fallback<<<grid, 256, 0, stream>>>(x, qw, scales, bias, out);
    }
}